// Round 1
// baseline (2108.575 us; speedup 1.0000x reference)
//
#include <hip/hip_runtime.h>
#include <math.h>

#define D_MODEL 1024
#define N_HEAD  16
#define DH      64
#define SEQ     2048
#define BATCH   4

// ---------------------------------------------------------------------------
// out[M=8192][N=1024] = X @ W^T + bias   (X:[M][1024] rm, W:[1024][1024] rm)
// If SPLIT_HEADS: write to [B,H,S,dh] layout instead of [M][N].
// 64x64 tile, 256 threads, 4x4 per thread, fp32.
// ---------------------------------------------------------------------------
template<bool SPLIT_HEADS>
__global__ __launch_bounds__(256) void gemm_xwT(const float* __restrict__ X,
                                                const float* __restrict__ W,
                                                const float* __restrict__ bias,
                                                float* __restrict__ out)
{
    const int K = D_MODEL;
    __shared__ float As[16][68];   // [k][m]
    __shared__ float Bs[16][68];   // [k][n]
    const int bm = blockIdx.x;     // 0..127 (row tiles)
    const int bn = blockIdx.y;     // 0..15  (col tiles)
    const int t  = threadIdx.x;
    const int tx = t & 15, ty = t >> 4;
    const int row0 = bm * 64, col0 = bn * 64;
    const int lr = t >> 2;          // 0..63
    const int lk = (t & 3) * 4;     // 0,4,8,12

    float acc[4][4] = {};

    for (int k0 = 0; k0 < K; k0 += 16) {
        float4 av = *(const float4*)(X + (size_t)(row0 + lr) * K + k0 + lk);
        float4 bv = *(const float4*)(W + (size_t)(col0 + lr) * K + k0 + lk);
        __syncthreads();   // previous iteration's LDS reads complete
        As[lk + 0][lr] = av.x; As[lk + 1][lr] = av.y;
        As[lk + 2][lr] = av.z; As[lk + 3][lr] = av.w;
        Bs[lk + 0][lr] = bv.x; Bs[lk + 1][lr] = bv.y;
        Bs[lk + 2][lr] = bv.z; Bs[lk + 3][lr] = bv.w;
        __syncthreads();
        #pragma unroll
        for (int kk = 0; kk < 16; ++kk) {
            float4 a = *(const float4*)&As[kk][ty * 4];
            float4 b = *(const float4*)&Bs[kk][tx * 4];
            float aa[4] = {a.x, a.y, a.z, a.w};
            float bb[4] = {b.x, b.y, b.z, b.w};
            #pragma unroll
            for (int i = 0; i < 4; ++i)
                #pragma unroll
                for (int j = 0; j < 4; ++j)
                    acc[i][j] = fmaf(aa[i], bb[j], acc[i][j]);
        }
    }

    #pragma unroll
    for (int i = 0; i < 4; ++i) {
        const int r = row0 + ty * 4 + i;
        #pragma unroll
        for (int j = 0; j < 4; ++j) {
            const int c = col0 + tx * 4 + j;
            const float v = acc[i][j] + bias[c];
            size_t idx;
            if (SPLIT_HEADS) {
                const int b = r >> 11, s = r & 2047;
                const int h = c >> 6,  d = c & 63;
                idx = (((size_t)(b * N_HEAD + h)) * SEQ + s) * DH + d;
            } else {
                idx = (size_t)r * D_MODEL + c;
            }
            out[idx] = v;
        }
    }
}

// ---------------------------------------------------------------------------
// Flash attention, fp32.  grid = (S/64, B*H), block = 256.
// qh/kh/vh: [B,H,S,dh].  ao: [B,S,D] (heads re-interleaved).
// ---------------------------------------------------------------------------
__global__ __launch_bounds__(256) void flash_attn(const float* __restrict__ qh,
                                                  const float* __restrict__ kh,
                                                  const float* __restrict__ vh,
                                                  float* __restrict__ ao)
{
    __shared__ float Qs[64][68];  // [d][qrow]
    __shared__ float Ks[64][68];  // [d][kcol]
    __shared__ float Vs[64][68];  // [krow][d]
    __shared__ float Ps[64][68];  // [kcol][qrow]

    const int bh = blockIdx.y;    // 0..63
    const int qt = blockIdx.x;    // 0..31
    const float* q = qh + (size_t)bh * SEQ * DH;
    const float* k = kh + (size_t)bh * SEQ * DH;
    const float* v = vh + (size_t)bh * SEQ * DH;

    const int t  = threadIdx.x;
    const int tx = t & 15, ty = t >> 4;
    const int lr = t >> 2;           // 0..63 (row to load)
    const int ld = (t & 3) * 16;     // 0,16,32,48

    // load Q tile transposed: Qs[d][r]
    #pragma unroll
    for (int u = 0; u < 4; ++u) {
        float4 x = *(const float4*)(q + (size_t)(qt * 64 + lr) * DH + ld + u * 4);
        Qs[ld + u * 4 + 0][lr] = x.x;
        Qs[ld + u * 4 + 1][lr] = x.y;
        Qs[ld + u * 4 + 2][lr] = x.z;
        Qs[ld + u * 4 + 3][lr] = x.w;
    }

    float m[4], l[4], O[4][4] = {};
    #pragma unroll
    for (int i = 0; i < 4; ++i) { m[i] = -INFINITY; l[i] = 0.f; }

    for (int kt = 0; kt < SEQ / 64; ++kt) {
        __syncthreads();  // prior PV reads of Ks/Vs/Ps done
        #pragma unroll
        for (int u = 0; u < 4; ++u) {
            float4 x = *(const float4*)(k + (size_t)(kt * 64 + lr) * DH + ld + u * 4);
            Ks[ld + u * 4 + 0][lr] = x.x;
            Ks[ld + u * 4 + 1][lr] = x.y;
            Ks[ld + u * 4 + 2][lr] = x.z;
            Ks[ld + u * 4 + 3][lr] = x.w;
            float4 y = *(const float4*)(v + (size_t)(kt * 64 + lr) * DH + ld + u * 4);
            *(float4*)&Vs[lr][ld + u * 4] = y;
        }
        __syncthreads();

        // S = Q K^T / 8  for this thread's 4x4
        float s[4][4] = {};
        #pragma unroll 8
        for (int d = 0; d < 64; ++d) {
            float4 a = *(const float4*)&Qs[d][ty * 4];
            float4 b = *(const float4*)&Ks[d][tx * 4];
            float aa[4] = {a.x, a.y, a.z, a.w};
            float bb[4] = {b.x, b.y, b.z, b.w};
            #pragma unroll
            for (int i = 0; i < 4; ++i)
                #pragma unroll
                for (int j = 0; j < 4; ++j)
                    s[i][j] = fmaf(aa[i], bb[j], s[i][j]);
        }

        // online softmax update (row r = qt*64 + ty*4+i, reduction across tx)
        #pragma unroll
        for (int i = 0; i < 4; ++i) {
            float rm = fmaxf(fmaxf(s[i][0], s[i][1]), fmaxf(s[i][2], s[i][3])) * 0.125f;
            #pragma unroll
            for (int mask = 1; mask < 16; mask <<= 1)
                rm = fmaxf(rm, __shfl_xor(rm, mask, 64));
            const float nm = fmaxf(m[i], rm);
            const float sc = expf(m[i] - nm);
            float rs = 0.f;
            #pragma unroll
            for (int j = 0; j < 4; ++j) {
                const float p = expf(s[i][j] * 0.125f - nm);
                s[i][j] = p;
                rs += p;
            }
            #pragma unroll
            for (int mask = 1; mask < 16; mask <<= 1)
                rs += __shfl_xor(rs, mask, 64);
            l[i] = l[i] * sc + rs;
            m[i] = nm;
            #pragma unroll
            for (int c = 0; c < 4; ++c) O[i][c] *= sc;
        }

        // stage P for the PV GEMM: Ps[kcol][qrow]
        #pragma unroll
        for (int i = 0; i < 4; ++i)
            #pragma unroll
            for (int j = 0; j < 4; ++j)
                Ps[tx * 4 + j][ty * 4 + i] = s[i][j];
        __syncthreads();

        // O += P V   (this thread: rows ty*4.., d-cols tx*4..)
        #pragma unroll 8
        for (int j = 0; j < 64; ++j) {
            float4 pa = *(const float4*)&Ps[j][ty * 4];
            float4 vv = *(const float4*)&Vs[j][tx * 4];
            float pp[4] = {pa.x, pa.y, pa.z, pa.w};
            float vb[4] = {vv.x, vv.y, vv.z, vv.w};
            #pragma unroll
            for (int i = 0; i < 4; ++i)
                #pragma unroll
                for (int c = 0; c < 4; ++c)
                    O[i][c] = fmaf(pp[i], vb[c], O[i][c]);
        }
    }

    const int b = bh >> 4, h = bh & 15;
    #pragma unroll
    for (int i = 0; i < 4; ++i) {
        const int r = qt * 64 + ty * 4 + i;
        const float inv = 1.0f / l[i];
        #pragma unroll
        for (int c = 0; c < 4; ++c) {
            const int d = tx * 4 + c;
            ao[((size_t)(b * SEQ + r)) * D_MODEL + h * DH + d] = O[i][c] * inv;
        }
    }
}

// ---------------------------------------------------------------------------
extern "C" void kernel_launch(void* const* d_in, const int* in_sizes, int n_in,
                              void* d_out, int out_size, void* d_ws, size_t ws_size,
                              hipStream_t stream)
{
    const float* Q  = (const float*)d_in[0];
    const float* K  = (const float*)d_in[1];
    const float* V  = (const float*)d_in[2];
    const float* Wq = (const float*)d_in[3];
    const float* bq = (const float*)d_in[4];
    const float* Wk = (const float*)d_in[5];
    const float* bk = (const float*)d_in[6];
    const float* Wv = (const float*)d_in[7];
    const float* bv = (const float*)d_in[8];
    const float* Wo = (const float*)d_in[9];
    const float* bo = (const float*)d_in[10];

    const size_t per = (size_t)BATCH * N_HEAD * SEQ * DH;  // 8.39M floats
    float* qh = (float*)d_ws;
    float* kh = qh + per;
    float* vh = kh + per;
    float* ao = vh + per;

    dim3 gb(128, 16);   // M/64 x N/64
    gemm_xwT<true><<<gb, 256, 0, stream>>>(Q, Wq, bq, qh);
    gemm_xwT<true><<<gb, 256, 0, stream>>>(K, Wk, bk, kh);
    gemm_xwT<true><<<gb, 256, 0, stream>>>(V, Wv, bv, vh);
    flash_attn<<<dim3(SEQ / 64, BATCH * N_HEAD), 256, 0, stream>>>(qh, kh, vh, ao);
    gemm_xwT<false><<<gb, 256, 0, stream>>>(ao, Wo, bo, (float*)d_out);
}

// Round 2
// 338.844 us; speedup vs baseline: 6.2228x; 6.2228x over previous
//
#include <hip/hip_runtime.h>
#include <math.h>

#define D_MODEL 1024
#define N_HEAD  16
#define DH      64
#define SEQ     2048
#define BATCH   4
#define BH      (BATCH*N_HEAD)   // 64
#define MROWS   (BATCH*SEQ)      // 8192

typedef __attribute__((ext_vector_type(8))) short          s16x8;
typedef __attribute__((ext_vector_type(8))) unsigned short u16x8;
typedef __attribute__((ext_vector_type(4))) unsigned short u16x4;
typedef __attribute__((ext_vector_type(4))) float          f32x4;

__device__ __forceinline__ unsigned short f2bf(float x) {
    unsigned int u = __float_as_uint(x);
    u += 0x7FFFu + ((u >> 16) & 1u);      // round-to-nearest-even
    return (unsigned short)(u >> 16);
}

// ---------------------------------------------------------------------------
// fp32 -> bf16, 8 elems/thread
// ---------------------------------------------------------------------------
__global__ __launch_bounds__(256) void conv_bf16(const float* __restrict__ in,
                                                 unsigned short* __restrict__ out,
                                                 int n8)
{
    int i = blockIdx.x * 256 + threadIdx.x;
    if (i >= n8) return;
    const float4* p = (const float4*)in + (size_t)i * 2;
    float4 a = p[0], b = p[1];
    u16x8 o;
    o[0] = f2bf(a.x); o[1] = f2bf(a.y); o[2] = f2bf(a.z); o[3] = f2bf(a.w);
    o[4] = f2bf(b.x); o[5] = f2bf(b.y); o[6] = f2bf(b.z); o[7] = f2bf(b.w);
    *((u16x8*)out + i) = o;
}

// ---------------------------------------------------------------------------
// C[M=8192][N=1024] = A(bf16)[M][1024] @ W(bf16)[N=1024][1024]^T + bias
// MODE 0: fp32 out [M][N]
// MODE 1: bf16 out split-head [B,H,S,dh]
// MODE 2: bf16 out transposed split-head [B,H,dh,S]
// 128x128 tile, BK=64, 256 threads (4 waves, 2x2), 4x4 16x16x32 frags/wave.
// ---------------------------------------------------------------------------
template<int MODE>
__global__ __launch_bounds__(256) void gemm_bt(const unsigned short* __restrict__ A,
                                               const unsigned short* __restrict__ W,
                                               const float* __restrict__ bias,
                                               unsigned short* __restrict__ outb,
                                               float* __restrict__ outf)
{
    __shared__ short As[128 * 64];   // [row][k] bf16, XOR-swizzled 16B groups
    __shared__ short Bs[128 * 64];
    const int tid = threadIdx.x;
    const int w = tid >> 6, l = tid & 63;
    const int lr = l & 15, lg = l >> 4;
    const int wm = w >> 1, wn = w & 1;
    const int r0 = blockIdx.x * 128, c0 = blockIdx.y * 128;
    const int srow = tid >> 3;   // 0..31
    const int sc8  = tid & 7;    // 0..7

    f32x4 zz = {0.f, 0.f, 0.f, 0.f};
    f32x4 acc[4][4];
    #pragma unroll
    for (int i = 0; i < 4; ++i)
        #pragma unroll
        for (int j = 0; j < 4; ++j) acc[i][j] = zz;

    u16x8 ar[4], br[4];
    #pragma unroll
    for (int p = 0; p < 4; ++p) {
        int row = p * 32 + srow;
        ar[p] = *(const u16x8*)(A + (size_t)(r0 + row) * 1024 + sc8 * 8);
        br[p] = *(const u16x8*)(W + (size_t)(c0 + row) * 1024 + sc8 * 8);
    }

    for (int ks = 0; ks < 16; ++ks) {
        __syncthreads();
        #pragma unroll
        for (int p = 0; p < 4; ++p) {
            int row = p * 32 + srow;
            *(u16x8*)&As[row * 64 + ((sc8 ^ (row & 7)) * 8)] = ar[p];
            *(u16x8*)&Bs[row * 64 + ((sc8 ^ (row & 7)) * 8)] = br[p];
        }
        __syncthreads();
        if (ks < 15) {
            int k0 = (ks + 1) * 64;
            #pragma unroll
            for (int p = 0; p < 4; ++p) {
                int row = p * 32 + srow;
                ar[p] = *(const u16x8*)(A + (size_t)(r0 + row) * 1024 + k0 + sc8 * 8);
                br[p] = *(const u16x8*)(W + (size_t)(c0 + row) * 1024 + k0 + sc8 * 8);
            }
        }
        #pragma unroll
        for (int t = 0; t < 2; ++t) {
            const int k8 = lg + 4 * t;
            s16x8 af[4], bw[4];
            #pragma unroll
            for (int i = 0; i < 4; ++i) {
                int rowa = wm * 64 + i * 16 + lr;
                af[i] = *(const s16x8*)&As[rowa * 64 + ((k8 ^ (rowa & 7)) * 8)];
                int rowb = wn * 64 + i * 16 + lr;
                bw[i] = *(const s16x8*)&Bs[rowb * 64 + ((k8 ^ (rowb & 7)) * 8)];
            }
            #pragma unroll
            for (int i = 0; i < 4; ++i)
                #pragma unroll
                for (int j = 0; j < 4; ++j)
                    acc[i][j] = __builtin_amdgcn_mfma_f32_16x16x32_bf16(af[i], bw[j], acc[i][j], 0, 0, 0);
        }
    }

    // epilogue: D row = (l>>4)*4 + reg, col = l&15 within each 16x16 frag
    #pragma unroll
    for (int i = 0; i < 4; ++i) {
        #pragma unroll
        for (int j = 0; j < 4; ++j) {
            const int colb = c0 + wn * 64 + j * 16 + lr;
            const float bv = bias[colb];
            if (MODE == 2) {
                const int row = r0 + wm * 64 + i * 16 + lg * 4;
                const int b = row >> 11, s = row & 2047;
                const int h = colb >> 6, d = colb & 63;
                u16x4 pv;
                pv[0] = f2bf(acc[i][j][0] + bv);
                pv[1] = f2bf(acc[i][j][1] + bv);
                pv[2] = f2bf(acc[i][j][2] + bv);
                pv[3] = f2bf(acc[i][j][3] + bv);
                *(u16x4*)(outb + ((size_t)(b * N_HEAD + h) * DH + d) * SEQ + s) = pv;
            } else {
                #pragma unroll
                for (int rg = 0; rg < 4; ++rg) {
                    const int row = r0 + wm * 64 + i * 16 + lg * 4 + rg;
                    const float v = acc[i][j][rg] + bv;
                    if (MODE == 0) {
                        outf[(size_t)row * D_MODEL + colb] = v;
                    } else {
                        const int b = row >> 11, s = row & 2047;
                        const int h = colb >> 6, d = colb & 63;
                        outb[((size_t)(b * N_HEAD + h) * SEQ + s) * DH + d] = f2bf(v);
                    }
                }
            }
        }
    }
}

// ---------------------------------------------------------------------------
// MFMA flash attention. grid = (S/64, B*H), block = 256 (4 waves).
// qb,kb: [B,H,S,dh] bf16.  vtb: [B,H,dh,S] bf16.  aob: [B,S,D] bf16.
// Each wave owns 16 q-rows; KV tile = 64.
// ---------------------------------------------------------------------------
__global__ __launch_bounds__(256) void flash_attn_mfma(const unsigned short* __restrict__ qb,
                                                       const unsigned short* __restrict__ kb,
                                                       const unsigned short* __restrict__ vtb,
                                                       unsigned short* __restrict__ aob)
{
    __shared__ short Kt[64 * 64];               // [kk][d] swizzled
    __shared__ short Vt[64 * 64];               // [d][kk] swizzled
    __shared__ unsigned short Ps[4][16 * 64];   // per-wave P, swizzled

    const int tid = threadIdx.x;
    const int w = tid >> 6, l = tid & 63;
    const int lr = l & 15, lg = l >> 4;
    const int qt = blockIdx.x, bh = blockIdx.y;
    const unsigned short* qh = qb + (size_t)bh * SEQ * DH;
    const unsigned short* kh = kb + (size_t)bh * SEQ * DH;
    const unsigned short* vh = vtb + (size_t)bh * DH * SEQ;

    s16x8 qf[2];
    #pragma unroll
    for (int t = 0; t < 2; ++t)
        qf[t] = *(const s16x8*)(qh + (size_t)(qt * 64 + w * 16 + lr) * DH + t * 32 + lg * 8);

    f32x4 zz = {0.f, 0.f, 0.f, 0.f};
    f32x4 O[4];
    float m[4], lsum[4];
    #pragma unroll
    for (int c = 0; c < 4; ++c) O[c] = zz;
    #pragma unroll
    for (int i = 0; i < 4; ++i) { m[i] = -1e30f; lsum[i] = 0.f; }

    const int srow = tid >> 3;   // 0..31
    const int sc8  = tid & 7;

    u16x8 kreg[2], vreg[2];
    #pragma unroll
    for (int p = 0; p < 2; ++p) {
        int rr = p * 32 + srow;
        kreg[p] = *(const u16x8*)(kh + (size_t)rr * DH + sc8 * 8);
        vreg[p] = *(const u16x8*)(vh + (size_t)rr * SEQ + sc8 * 8);
    }

    for (int kv = 0; kv < SEQ / 64; ++kv) {
        __syncthreads();
        #pragma unroll
        for (int p = 0; p < 2; ++p) {
            int rr = p * 32 + srow;
            *(u16x8*)&Kt[rr * 64 + ((sc8 ^ (rr & 7)) * 8)] = kreg[p];
            *(u16x8*)&Vt[rr * 64 + ((sc8 ^ (rr & 7)) * 8)] = vreg[p];
        }
        __syncthreads();
        if (kv < SEQ / 64 - 1) {
            const int s0 = (kv + 1) * 64;
            #pragma unroll
            for (int p = 0; p < 2; ++p) {
                int rr = p * 32 + srow;
                kreg[p] = *(const u16x8*)(kh + (size_t)(s0 + rr) * DH + sc8 * 8);
                vreg[p] = *(const u16x8*)(vh + (size_t)rr * SEQ + s0 + sc8 * 8);
            }
        }

        // S = Q K^T  (16 rows x 64 cols per wave)
        f32x4 sc[4];
        #pragma unroll
        for (int c = 0; c < 4; ++c) sc[c] = zz;
        #pragma unroll
        for (int t = 0; t < 2; ++t) {
            const int k8 = lg + 4 * t;
            #pragma unroll
            for (int c = 0; c < 4; ++c) {
                const int rk = c * 16 + lr;
                s16x8 kf = *(const s16x8*)&Kt[rk * 64 + ((k8 ^ (rk & 7)) * 8)];
                sc[c] = __builtin_amdgcn_mfma_f32_16x16x32_bf16(qf[t], kf, sc[c], 0, 0, 0);
            }
        }

        // wave-parallel online softmax (row = lg*4 + i, reduce over 16 lanes)
        #pragma unroll
        for (int i = 0; i < 4; ++i) {
            float rm = fmaxf(fmaxf(sc[0][i], sc[1][i]), fmaxf(sc[2][i], sc[3][i])) * 0.125f;
            rm = fmaxf(rm, __shfl_xor(rm, 1, 64));
            rm = fmaxf(rm, __shfl_xor(rm, 2, 64));
            rm = fmaxf(rm, __shfl_xor(rm, 4, 64));
            rm = fmaxf(rm, __shfl_xor(rm, 8, 64));
            const float nm = fmaxf(m[i], rm);
            const float f = __expf(m[i] - nm);
            float pc[4];
            float rs = 0.f;
            #pragma unroll
            for (int c = 0; c < 4; ++c) {
                pc[c] = __expf(sc[c][i] * 0.125f - nm);
                rs += pc[c];
            }
            rs += __shfl_xor(rs, 1, 64);
            rs += __shfl_xor(rs, 2, 64);
            rs += __shfl_xor(rs, 4, 64);
            rs += __shfl_xor(rs, 8, 64);
            lsum[i] = lsum[i] * f + rs;
            m[i] = nm;
            #pragma unroll
            for (int c = 0; c < 4; ++c) O[c][i] *= f;
            const int pr = lg * 4 + i;
            #pragma unroll
            for (int c = 0; c < 4; ++c)
                Ps[w][pr * 64 + ((c * 16 + lr) ^ ((pr & 7) << 3))] = f2bf(pc[c]);
        }

        asm volatile("s_waitcnt lgkmcnt(0)" ::: "memory");

        // O += P V
        #pragma unroll
        for (int t = 0; t < 2; ++t) {
            const int k8 = lg + 4 * t;
            s16x8 pf = *(const s16x8*)&Ps[w][lr * 64 + ((k8 ^ (lr & 7)) * 8)];
            #pragma unroll
            for (int c = 0; c < 4; ++c) {
                const int rd = c * 16 + lr;
                s16x8 vf = *(const s16x8*)&Vt[rd * 64 + ((k8 ^ (rd & 7)) * 8)];
                O[c] = __builtin_amdgcn_mfma_f32_16x16x32_bf16(pf, vf, O[c], 0, 0, 0);
            }
        }
    }

    const int b = bh >> 4, h = bh & 15;
    #pragma unroll
    for (int i = 0; i < 4; ++i) {
        const float inv = 1.0f / lsum[i];
        const int row = qt * 64 + w * 16 + lg * 4 + i;
        #pragma unroll
        for (int c = 0; c < 4; ++c) {
            const int col = h * DH + c * 16 + lr;
            aob[((size_t)b * SEQ + row) * D_MODEL + col] = f2bf(O[c][i] * inv);
        }
    }
}

// ---------------------------------------------------------------------------
extern "C" void kernel_launch(void* const* d_in, const int* in_sizes, int n_in,
                              void* d_out, int out_size, void* d_ws, size_t ws_size,
                              hipStream_t stream)
{
    const float* Q  = (const float*)d_in[0];
    const float* K  = (const float*)d_in[1];
    const float* V  = (const float*)d_in[2];
    const float* Wq = (const float*)d_in[3];
    const float* bq = (const float*)d_in[4];
    const float* Wk = (const float*)d_in[5];
    const float* bk = (const float*)d_in[6];
    const float* Wv = (const float*)d_in[7];
    const float* bv = (const float*)d_in[8];
    const float* Wo = (const float*)d_in[9];
    const float* bo = (const float*)d_in[10];

    const size_t PER = (size_t)MROWS * D_MODEL;           // 8388608
    unsigned short* Xb  = (unsigned short*)d_ws;
    unsigned short* Wb  = Xb + PER;
    unsigned short* qb2 = Wb + (size_t)D_MODEL * D_MODEL;
    unsigned short* kb2 = qb2 + PER;
    unsigned short* vtb = kb2 + PER;
    unsigned short* aob = vtb + PER;

    const int nX8 = (int)(PER / 8);              // 1048576
    const int nW8 = D_MODEL * D_MODEL / 8;       // 131072
    dim3 gg(MROWS / 128, D_MODEL / 128);         // 64 x 8

    conv_bf16<<<nX8 / 256, 256, 0, stream>>>(Q, Xb, nX8);
    conv_bf16<<<nW8 / 256, 256, 0, stream>>>(Wq, Wb, nW8);
    gemm_bt<1><<<gg, 256, 0, stream>>>(Xb, Wb, bq, qb2, nullptr);

    conv_bf16<<<nX8 / 256, 256, 0, stream>>>(K, Xb, nX8);
    conv_bf16<<<nW8 / 256, 256, 0, stream>>>(Wk, Wb, nW8);
    gemm_bt<1><<<gg, 256, 0, stream>>>(Xb, Wb, bk, kb2, nullptr);

    conv_bf16<<<nX8 / 256, 256, 0, stream>>>(V, Xb, nX8);
    conv_bf16<<<nW8 / 256, 256, 0, stream>>>(Wv, Wb, nW8);
    gemm_bt<2><<<gg, 256, 0, stream>>>(Xb, Wb, bv, vtb, nullptr);

    flash_attn_mfma<<<dim3(SEQ / 64, BH), 256, 0, stream>>>(qb2, kb2, vtb, aob);

    conv_bf16<<<nW8 / 256, 256, 0, stream>>>(Wo, Wb, nW8);
    gemm_bt<0><<<gg, 256, 0, stream>>>(aob, Wb, bo, nullptr, (float*)d_out);
}

// Round 3
// 280.184 us; speedup vs baseline: 7.5257x; 1.2094x over previous
//
#include <hip/hip_runtime.h>
#include <math.h>

#define D_MODEL 1024
#define N_HEAD  16
#define DH      64
#define SEQ     2048
#define BATCH   4
#define BH      (BATCH*N_HEAD)   // 64
#define MROWS   (BATCH*SEQ)      // 8192

typedef __attribute__((ext_vector_type(8)))  short          s16x8;
typedef __attribute__((ext_vector_type(8)))  unsigned short u16x8;
typedef __attribute__((ext_vector_type(4)))  unsigned short u16x4;
typedef __attribute__((ext_vector_type(4)))  float          f32x4;
typedef __attribute__((ext_vector_type(16))) float          f32x16;
typedef __attribute__((ext_vector_type(4)))  unsigned int   u32x4;

__device__ __forceinline__ unsigned short f2bf(float x) {
    unsigned int u = __float_as_uint(x);
    u += 0x7FFFu + ((u >> 16) & 1u);      // round-to-nearest-even
    return (unsigned short)(u >> 16);
}

__device__ __forceinline__ unsigned int cvtpk_bf16(float lo, float hi) {
    unsigned int r;
    asm("v_cvt_pk_bf16_f32 %0, %1, %2" : "=v"(r) : "v"(lo), "v"(hi));
    return r;
}

// ---------------------------------------------------------------------------
// fp32 -> bf16, 8 elems/thread
// ---------------------------------------------------------------------------
__global__ __launch_bounds__(256) void conv_bf16(const float* __restrict__ in,
                                                 unsigned short* __restrict__ out,
                                                 int n8)
{
    int i = blockIdx.x * 256 + threadIdx.x;
    if (i >= n8) return;
    const float4* p = (const float4*)in + (size_t)i * 2;
    float4 a = p[0], b = p[1];
    u16x8 o;
    o[0] = f2bf(a.x); o[1] = f2bf(a.y); o[2] = f2bf(a.z); o[3] = f2bf(a.w);
    o[4] = f2bf(b.x); o[5] = f2bf(b.y); o[6] = f2bf(b.z); o[7] = f2bf(b.w);
    *((u16x8*)out + i) = o;
}

// ---------------------------------------------------------------------------
// C[M=8192][N=1024] = A(bf16)[M][1024] @ W(bf16)[N=1024][1024]^T + bias
// MODE 0: fp32 out [M][N]
// MODE 1: bf16 out split-head [B,H,S,dh]
// MODE 2: bf16 out transposed split-head [B,H,dh,S]
// ---------------------------------------------------------------------------
template<int MODE>
__global__ __launch_bounds__(256) void gemm_bt(const unsigned short* __restrict__ A,
                                               const unsigned short* __restrict__ W,
                                               const float* __restrict__ bias,
                                               unsigned short* __restrict__ outb,
                                               float* __restrict__ outf)
{
    __shared__ short As[128 * 64];   // [row][k] bf16, XOR-swizzled 16B groups
    __shared__ short Bs[128 * 64];
    const int tid = threadIdx.x;
    const int w = tid >> 6, l = tid & 63;
    const int lr = l & 15, lg = l >> 4;
    const int wm = w >> 1, wn = w & 1;
    const int r0 = blockIdx.x * 128, c0 = blockIdx.y * 128;
    const int srow = tid >> 3;   // 0..31
    const int sc8  = tid & 7;    // 0..7

    f32x4 zz = {0.f, 0.f, 0.f, 0.f};
    f32x4 acc[4][4];
    #pragma unroll
    for (int i = 0; i < 4; ++i)
        #pragma unroll
        for (int j = 0; j < 4; ++j) acc[i][j] = zz;

    u16x8 ar[4], br[4];
    #pragma unroll
    for (int p = 0; p < 4; ++p) {
        int row = p * 32 + srow;
        ar[p] = *(const u16x8*)(A + (size_t)(r0 + row) * 1024 + sc8 * 8);
        br[p] = *(const u16x8*)(W + (size_t)(c0 + row) * 1024 + sc8 * 8);
    }

    for (int ks = 0; ks < 16; ++ks) {
        __syncthreads();
        #pragma unroll
        for (int p = 0; p < 4; ++p) {
            int row = p * 32 + srow;
            *(u16x8*)&As[row * 64 + ((sc8 ^ (row & 7)) * 8)] = ar[p];
            *(u16x8*)&Bs[row * 64 + ((sc8 ^ (row & 7)) * 8)] = br[p];
        }
        __syncthreads();
        if (ks < 15) {
            int k0 = (ks + 1) * 64;
            #pragma unroll
            for (int p = 0; p < 4; ++p) {
                int row = p * 32 + srow;
                ar[p] = *(const u16x8*)(A + (size_t)(r0 + row) * 1024 + k0 + sc8 * 8);
                br[p] = *(const u16x8*)(W + (size_t)(c0 + row) * 1024 + k0 + sc8 * 8);
            }
        }
        #pragma unroll
        for (int t = 0; t < 2; ++t) {
            const int k8 = lg + 4 * t;
            s16x8 af[4], bw[4];
            #pragma unroll
            for (int i = 0; i < 4; ++i) {
                int rowa = wm * 64 + i * 16 + lr;
                af[i] = *(const s16x8*)&As[rowa * 64 + ((k8 ^ (rowa & 7)) * 8)];
                int rowb = wn * 64 + i * 16 + lr;
                bw[i] = *(const s16x8*)&Bs[rowb * 64 + ((k8 ^ (rowb & 7)) * 8)];
            }
            #pragma unroll
            for (int i = 0; i < 4; ++i)
                #pragma unroll
                for (int j = 0; j < 4; ++j)
                    acc[i][j] = __builtin_amdgcn_mfma_f32_16x16x32_bf16(af[i], bw[j], acc[i][j], 0, 0, 0);
        }
    }

    #pragma unroll
    for (int i = 0; i < 4; ++i) {
        #pragma unroll
        for (int j = 0; j < 4; ++j) {
            const int colb = c0 + wn * 64 + j * 16 + lr;
            const float bv = bias[colb];
            if (MODE == 2) {
                const int row = r0 + wm * 64 + i * 16 + lg * 4;
                const int b = row >> 11, s = row & 2047;
                const int h = colb >> 6, d = colb & 63;
                u16x4 pv;
                pv[0] = f2bf(acc[i][j][0] + bv);
                pv[1] = f2bf(acc[i][j][1] + bv);
                pv[2] = f2bf(acc[i][j][2] + bv);
                pv[3] = f2bf(acc[i][j][3] + bv);
                *(u16x4*)(outb + ((size_t)(b * N_HEAD + h) * DH + d) * SEQ + s) = pv;
            } else {
                #pragma unroll
                for (int rg = 0; rg < 4; ++rg) {
                    const int row = r0 + wm * 64 + i * 16 + lg * 4 + rg;
                    const float v = acc[i][j][rg] + bv;
                    if (MODE == 0) {
                        outf[(size_t)row * D_MODEL + colb] = v;
                    } else {
                        const int b = row >> 11, s = row & 2047;
                        const int h = colb >> 6, d = colb & 63;
                        outb[((size_t)(b * N_HEAD + h) * SEQ + s) * DH + d] = f2bf(v);
                    }
                }
            }
        }
    }
}

// ---------------------------------------------------------------------------
// Swapped-operand MFMA flash attention (32x32x16).
// grid = (S/128, B*H), block = 256 (4 waves x 32 q-rows).
// qb,kb: [B,H,S,dh] bf16.  vtb: [B,H,dh,S] bf16.  aob: [B,S,D] bf16.
// S^T = mfma(K,Q): lane&31 = q-row, regs = kv  -> lane-local softmax.
// O^T = mfma(V^T,P^T): lane&31 = q-row, regs = d -> free rescale.
// ---------------------------------------------------------------------------
__global__ __launch_bounds__(256) void flash_attn_mfma32(const unsigned short* __restrict__ qb,
                                                         const unsigned short* __restrict__ kb,
                                                         const unsigned short* __restrict__ vtb,
                                                         unsigned short* __restrict__ aob)
{
    __shared__ short Kt[64 * 64];   // [kv][d]  swizzled 16B groups
    __shared__ short Vt[64 * 64];   // [d][kv]  swizzled 16B groups

    const int tid = threadIdx.x;
    const int w = tid >> 6, l = tid & 63;
    const int q32 = l & 31;          // lane's q-row within wave tile
    const int h = l >> 5;            // lane half
    const int qt = blockIdx.x, bh = blockIdx.y;
    const unsigned short* qh = qb + (size_t)bh * SEQ * DH;
    const unsigned short* kh = kb + (size_t)bh * SEQ * DH;
    const unsigned short* vh = vtb + (size_t)bh * DH * SEQ;

    const int qrow = qt * 128 + w * 32 + q32;

    // Q fragments (B operand): col = q = l&31, k = ks*16 + h*8 + e
    s16x8 qf[4];
    #pragma unroll
    for (int ks = 0; ks < 4; ++ks)
        qf[ks] = *(const s16x8*)(qh + (size_t)qrow * DH + ks * 16 + h * 8);

    f32x16 O[2];
    #pragma unroll
    for (int c = 0; c < 2; ++c)
        #pragma unroll
        for (int r = 0; r < 16; ++r) O[c][r] = 0.f;
    float m = -1e30f, lsum = 0.f;

    const int srow = tid >> 3;   // 0..31
    const int sc8  = tid & 7;

    u16x8 kreg[2], vreg[2];
    #pragma unroll
    for (int p = 0; p < 2; ++p) {
        int rr = p * 32 + srow;
        kreg[p] = *(const u16x8*)(kh + (size_t)rr * DH + sc8 * 8);
        vreg[p] = *(const u16x8*)(vh + (size_t)rr * SEQ + sc8 * 8);
    }

    for (int kv = 0; kv < SEQ / 64; ++kv) {
        __syncthreads();
        #pragma unroll
        for (int p = 0; p < 2; ++p) {
            int rr = p * 32 + srow;
            *(u16x8*)&Kt[rr * 64 + ((sc8 ^ (rr & 7)) * 8)] = kreg[p];
            *(u16x8*)&Vt[rr * 64 + ((sc8 ^ (rr & 7)) * 8)] = vreg[p];
        }
        __syncthreads();
        if (kv < SEQ / 64 - 1) {
            const int s0 = (kv + 1) * 64;
            #pragma unroll
            for (int p = 0; p < 2; ++p) {
                int rr = p * 32 + srow;
                kreg[p] = *(const u16x8*)(kh + (size_t)(s0 + rr) * DH + sc8 * 8);
                vreg[p] = *(const u16x8*)(vh + (size_t)rr * SEQ + s0 + sc8 * 8);
            }
        }

        // ---- S^T = K . Q^T : SC[c] covers kv = 32c..32c+31 for q-row (l&31)
        f32x16 SC[2];
        #pragma unroll
        for (int c = 0; c < 2; ++c)
            #pragma unroll
            for (int r = 0; r < 16; ++r) SC[c][r] = 0.f;
        #pragma unroll
        for (int ks = 0; ks < 4; ++ks) {
            #pragma unroll
            for (int c = 0; c < 2; ++c) {
                const int row = c * 32 + q32;
                s16x8 kf = *(const s16x8*)&Kt[row * 64 + (((2 * ks + h) ^ (row & 7)) * 8)];
                SC[c] = __builtin_amdgcn_mfma_f32_32x32x16_bf16(kf, qf[ks], SC[c], 0, 0, 0);
            }
        }

        // ---- lane-local online softmax (kv(reg) = 32c + (r&3) + 8*(r>>2) + 4h)
        float t0[8];
        #pragma unroll
        for (int r = 0; r < 8; ++r)
            t0[r] = fmaxf(fmaxf(SC[0][r], SC[0][r + 8]), fmaxf(SC[1][r], SC[1][r + 8]));
        #pragma unroll
        for (int d = 4; d; d >>= 1)
            #pragma unroll
            for (int r = 0; r < d; ++r) t0[r] = fmaxf(t0[r], t0[r + d]);
        float rm = fmaxf(t0[0], __shfl_xor(t0[0], 32, 64));

        const float nm = fmaxf(m, rm);
        const float fold = __expf((m - nm) * 0.125f);
        const float nm8 = nm * 0.125f;
        #pragma unroll
        for (int c = 0; c < 2; ++c)
            #pragma unroll
            for (int r = 0; r < 16; ++r)
                SC[c][r] = __expf(__builtin_fmaf(SC[c][r], 0.125f, -nm8));
        float s0a[8];
        #pragma unroll
        for (int r = 0; r < 8; ++r)
            s0a[r] = (SC[0][r] + SC[0][r + 8]) + (SC[1][r] + SC[1][r + 8]);
        #pragma unroll
        for (int d = 4; d; d >>= 1)
            #pragma unroll
            for (int r = 0; r < d; ++r) s0a[r] += s0a[r + d];
        float rs = s0a[0] + __shfl_xor(s0a[0], 32, 64);

        lsum = lsum * fold + rs;
        m = nm;
        O[0] *= fold;
        O[1] *= fold;

        // ---- pack P^T fragments in-register (B operand: col=q, k=kv chunk)
        s16x8 pa[4];
        #pragma unroll
        for (int s = 0; s < 4; ++s) {
            const int c = s >> 1, rb = (s & 1) * 8;
            unsigned int a0 = cvtpk_bf16(SC[c][rb + 0], SC[c][rb + 1]);
            unsigned int a1 = cvtpk_bf16(SC[c][rb + 2], SC[c][rb + 3]);
            unsigned int b0 = cvtpk_bf16(SC[c][rb + 4], SC[c][rb + 5]);
            unsigned int b1 = cvtpk_bf16(SC[c][rb + 6], SC[c][rb + 7]);
            unsigned int x0 = (unsigned int)__shfl_xor((int)a0, 32, 64);
            unsigned int x1 = (unsigned int)__shfl_xor((int)a1, 32, 64);
            unsigned int y0 = (unsigned int)__shfl_xor((int)b0, 32, 64);
            unsigned int y1 = (unsigned int)__shfl_xor((int)b1, 32, 64);
            u32x4 wd;
            wd[0] = h ? y0 : a0;
            wd[1] = h ? y1 : a1;
            wd[2] = h ? b0 : x0;
            wd[3] = h ? b1 : x1;
            pa[s] = __builtin_bit_cast(s16x8, wd);
        }

        // ---- O^T += V^T . P^T  (A = V^T from Vt, B = pa)
        #pragma unroll
        for (int s = 0; s < 4; ++s) {
            #pragma unroll
            for (int c = 0; c < 2; ++c) {
                const int row = c * 32 + q32;
                s16x8 vf = *(const s16x8*)&Vt[row * 64 + (((2 * s + h) ^ (row & 7)) * 8)];
                O[c] = __builtin_amdgcn_mfma_f32_32x32x16_bf16(vf, pa[s], O[c], 0, 0, 0);
            }
        }
    }

    // ---- epilogue: O^T[d][q]: d = (r&3) + 8*(r>>2) + 4h + 32c, q = qrow
    const float inv = 1.0f / lsum;
    const int b = bh >> 4, head = bh & 15;
    unsigned short* obase = aob + ((size_t)b * SEQ + qrow) * D_MODEL + head * DH;
    #pragma unroll
    for (int c = 0; c < 2; ++c) {
        #pragma unroll
        for (int rq = 0; rq < 4; ++rq) {
            const int d0 = 8 * rq + 4 * h + 32 * c;
            u16x4 pv;
            #pragma unroll
            for (int j = 0; j < 4; ++j) pv[j] = f2bf(O[c][rq * 4 + j] * inv);
            *(u16x4*)(obase + d0) = pv;
        }
    }
}

// ---------------------------------------------------------------------------
extern "C" void kernel_launch(void* const* d_in, const int* in_sizes, int n_in,
                              void* d_out, int out_size, void* d_ws, size_t ws_size,
                              hipStream_t stream)
{
    const float* Q  = (const float*)d_in[0];
    const float* K  = (const float*)d_in[1];
    const float* V  = (const float*)d_in[2];
    const float* Wq = (const float*)d_in[3];
    const float* bq = (const float*)d_in[4];
    const float* Wk = (const float*)d_in[5];
    const float* bk = (const float*)d_in[6];
    const float* Wv = (const float*)d_in[7];
    const float* bv = (const float*)d_in[8];
    const float* Wo = (const float*)d_in[9];
    const float* bo = (const float*)d_in[10];

    const size_t PER = (size_t)MROWS * D_MODEL;           // 8388608
    unsigned short* Xb  = (unsigned short*)d_ws;
    unsigned short* Wb  = Xb + PER;
    unsigned short* qb2 = Wb + (size_t)D_MODEL * D_MODEL;
    unsigned short* kb2 = qb2 + PER;
    unsigned short* vtb = kb2 + PER;
    unsigned short* aob = vtb + PER;

    const int nX8 = (int)(PER / 8);              // 1048576
    const int nW8 = D_MODEL * D_MODEL / 8;       // 131072
    dim3 gg(MROWS / 128, D_MODEL / 128);         // 64 x 8

    conv_bf16<<<nX8 / 256, 256, 0, stream>>>(Q, Xb, nX8);
    conv_bf16<<<nW8 / 256, 256, 0, stream>>>(Wq, Wb, nW8);
    gemm_bt<1><<<gg, 256, 0, stream>>>(Xb, Wb, bq, qb2, nullptr);

    conv_bf16<<<nX8 / 256, 256, 0, stream>>>(K, Xb, nX8);
    conv_bf16<<<nW8 / 256, 256, 0, stream>>>(Wk, Wb, nW8);
    gemm_bt<1><<<gg, 256, 0, stream>>>(Xb, Wb, bk, kb2, nullptr);

    conv_bf16<<<nX8 / 256, 256, 0, stream>>>(V, Xb, nX8);
    conv_bf16<<<nW8 / 256, 256, 0, stream>>>(Wv, Wb, nW8);
    gemm_bt<2><<<gg, 256, 0, stream>>>(Xb, Wb, bv, vtb, nullptr);

    flash_attn_mfma32<<<dim3(SEQ / 128, BH), 256, 0, stream>>>(qb2, kb2, vtb, aob);

    conv_bf16<<<nW8 / 256, 256, 0, stream>>>(Wo, Wb, nW8);
    gemm_bt<0><<<gg, 256, 0, stream>>>(aob, Wb, bo, nullptr, (float*)d_out);
}